// Round 12
// baseline (50161.337 us; speedup 1.0000x reference)
//
// Round 12: r11 + correct exchange fences (the only change).
// Rule (3-for-3 empirical: r4/r7/r11 fail, r1/r2/r6 pass): cross-WG data needs
// a RELEASE fence in the producing wave before the flag store and an ACQUIRE
// fence in the consuming wave before the data loads. r11 passed data through
// relaxed agent atomics with no fences -> stale reads (absmax 0.234).
// Here: data stores all in wave 0 (lid<50); release fence in wave 0 precedes
// flag store (in-wave order). Consumers poll relaxed, then acquire fence in
// the polling wave, then data loads by the same threads (in-wave inv->load,
// the r5->r6-proven pattern). ~13 cache ops/WG/step vs r6's 16384.

#include <hip/hip_runtime.h>
#include <hip/hip_cooperative_groups.h>

namespace cg = cooperative_groups;

#define HH 400
#define NK 10
#define VV 77
#define NO 121
#define TT 600
#define UU 64

#define NWG 256
#define NTH 1024

#define NG1  60     // L1: K=480 -> 60 uint4 groups
#define NG23 110    // L2/L3: K=880

// u32 offsets in ws
#define O_L1  0
#define O_L2  384000
#define O_L3  1088000
#define O_OUT 1792000     // repacked [q][600 kp][32 oi], o = 4*oi+q
#define O_WW  1868800     // Wwin f16: 60 lanes x 100 u32
#define O_XC  1874800     // exchange: [item][phase*256 + q*64 + i], 768/item
#define O_FL  1923952     // flags: [item*64 + q*16]
#define N_END 1928048     // 7.71 MB

typedef _Float16 h2 __attribute__((ext_vector_type(2)));

struct Args {
  const float* __restrict__ x;
  const int*   __restrict__ text;
  const float* __restrict__ mask;
  const float* __restrict__ Wih1; const float* __restrict__ Whh1; const float* __restrict__ b1;
  const float* __restrict__ Wih2; const float* __restrict__ Whh2; const float* __restrict__ b2;
  const float* __restrict__ Wih3; const float* __restrict__ Whh3; const float* __restrict__ b3;
  const float* __restrict__ Wwin; const float* __restrict__ bwin;
  const float* __restrict__ Wout; const float* __restrict__ bout;
  float* __restrict__ out;
  float* __restrict__ ws;
};

__device__ __forceinline__ float sigm(float v) { return 1.0f / (1.0f + __expf(-v)); }

#if defined(__has_builtin)
#if __has_builtin(__builtin_amdgcn_fdot2)
#define FDOT2(a,b,c) __builtin_amdgcn_fdot2((a),(b),(c),false)
#endif
#endif
#ifndef FDOT2
#define FDOT2(a,b,c) fmaf((float)(a).x,(float)(b).x, fmaf((float)(a).y,(float)(b).y,(c)))
#endif

__device__ __forceinline__ h2 toh2(unsigned int u) { return __builtin_bit_cast(h2, u); }

__device__ __forceinline__ float dot4(uint4 p, uint4 v, float a) {
  a = FDOT2(toh2(p.x), toh2(v.x), a);
  a = FDOT2(toh2(p.y), toh2(v.y), a);
  a = FDOT2(toh2(p.z), toh2(v.z), a);
  a = FDOT2(toh2(p.w), toh2(v.w), a);
  return a;
}

__device__ __forceinline__ unsigned int packh2(float f0, float f1) {
  unsigned short lo = __builtin_bit_cast(unsigned short, (_Float16)f0);
  unsigned short hi = __builtin_bit_cast(unsigned short, (_Float16)f1);
  return (unsigned int)lo | ((unsigned int)hi << 16);
}

// Row-band gate matvec: 400 rows (4 gate bands x 100 cells), K split in halves.
template<int NGR>
__device__ __forceinline__ void gatesB(const unsigned int* __restrict__ Wu,
    const _Float16* __restrict__ svh, float* __restrict__ pp, int rowbase, int lid)
{
  int r2 = lid & 127, gi = (lid >> 7) & 3, kh = lid >> 9;
  if (r2 < 100) {
    const uint4* W4 = (const uint4*)Wu + (gi * 400 + rowbase + r2);
    const uint4* vp = (const uint4*)svh;
    constexpr int HG = NGR / 2;
    float a = 0.f;
    #pragma unroll 5
    for (int g = kh * HG; g < kh * HG + HG; ++g)
      a = dot4(W4[(size_t)g * 1600], vp[g], a);
    pp[kh * 512 + gi * 128 + r2] = a;
  }
}

__global__ __launch_bounds__(1024) void hsnet_kernel(Args A) {
  cg::grid_group grid = cg::this_grid();
  const int lid  = threadIdx.x;
  const int bid  = blockIdx.x;
  const int q    = bid >> 6;     // cluster rank 0..3 (row band)
  const int item = bid & 63;
  const int lane = lid & 63;
  const int wv   = lid >> 6;
  unsigned int* __restrict__ wsu = (unsigned int*)A.ws;

  // ===== prologue: weight conversion + zero exchange/flags =====
  for (int i = bid * NTH + lid; i < N_END; i += NWG * NTH) {
    if (i >= O_XC) { wsu[i] = 0u; continue; }
    float f0, f1;
    if (i < O_L2) {
      int u = i, g = u / 6400, rem = u - g * 6400, r = rem >> 2, jj = rem & 3;
      int k0 = 8 * g + 2 * jj;
      if (k0 < 80) { f0 = A.Wih1[r * 80 + k0];       f1 = A.Wih1[r * 80 + k0 + 1]; }
      else         { f0 = A.Whh1[r * 400 + k0 - 80]; f1 = A.Whh1[r * 400 + k0 - 79]; }
    } else if (i < O_L3) {
      int u = i - O_L2, g = u / 6400, rem = u - g * 6400, r = rem >> 2, jj = rem & 3;
      int k0 = 8 * g + 2 * jj;
      if (k0 < 480) { f0 = A.Wih2[r * 480 + k0];        f1 = A.Wih2[r * 480 + k0 + 1]; }
      else          { f0 = A.Whh2[r * 400 + k0 - 480];  f1 = A.Whh2[r * 400 + k0 - 479]; }
    } else if (i < O_OUT) {
      int u = i - O_L3, g = u / 6400, rem = u - g * 6400, r = rem >> 2, jj = rem & 3;
      int k0 = 8 * g + 2 * jj;
      if (k0 < 480) { f0 = A.Wih3[r * 480 + k0];        f1 = A.Wih3[r * 480 + k0 + 1]; }
      else          { f0 = A.Whh3[r * 400 + k0 - 480];  f1 = A.Whh3[r * 400 + k0 - 479]; }
    } else if (i < O_WW) {                   // Wout repack [q4][kp][oi], o=4*oi+q4
      int u = i - O_OUT, q4 = u / 19200, rem = u - q4 * 19200;
      int kp = rem >> 5, oi = rem & 31, o = 4 * oi + q4, k0 = 2 * kp;
      f0 = (o < NO) ? A.Wout[o * 1200 + k0]     : 0.0f;
      f1 = (o < NO) ? A.Wout[o * 1200 + k0 + 1] : 0.0f;
    } else {                                 // Wwin f16: ln=2g+half, 100 u32 each
      int u = i - O_WW, ln = u / 100, p = u - ln * 100;
      int g = ln >> 1, half = ln & 1, k0 = half * 200 + 2 * p;
      f0 = A.Wwin[g * HH + k0]; f1 = A.Wwin[g * HH + k0 + 1];
    }
    wsu[i] = packh2(f0, f1);
  }
  grid.sync();   // sole grid-wide event

  const unsigned int* __restrict__ WL1  = wsu + O_L1;
  const unsigned int* __restrict__ WL2  = wsu + O_L2;
  const unsigned int* __restrict__ WL3  = wsu + O_L3;
  const unsigned int* __restrict__ WOq  = wsu + O_OUT + q * 19200;
  const unsigned int* __restrict__ WWIN = wsu + O_WW;
  unsigned int* xit = wsu + O_XC + item * 768;
  unsigned int* flb = wsu + O_FL + item * 64;

  __shared__ alignas(16) _Float16 svh1[480];   // L1 in: [x3, w77, h1 400]
  __shared__ alignas(16) _Float16 svh2[880];   // L2 in: [x3, h1, w77, h2]
  __shared__ alignas(16) _Float16 svh3[880];   // L3 in: [x3, h2, w77, h3]
  __shared__ alignas(16) _Float16 soh[1200];   // [h1|h2|h3] current step
  __shared__ float pp[1024];                   // gate partials [kh][gi][128]
  __shared__ float pO[32][32];                 // out partials [kp][oi]

  if (lid < 480) svh1[lid] = (_Float16)0.f;
  if (lid < 880) { svh2[lid] = (_Float16)0.f; svh3[lid] = (_Float16)0.f; }
  if (lid < 600) { soh[lid] = (_Float16)0.f; soh[600 + lid] = (_Float16)0.f; }
  if (lid < 3) svh1[lid] = (_Float16)A.x[(size_t)item * TT * 3 + lid];

  float2 c1 = {0.f, 0.f}, c2r = {0.f, 0.f}, c3r = {0.f, 0.f};
  float kapr[NK];
  #pragma unroll
  for (int k = 0; k < NK; ++k) kapr[k] = 0.f;
  float maskr = A.mask[item * UU + lane];
  int   textr = A.text[item * UU + lane];
  float bwinr = (lane < 60 && !(lane & 1)) ? A.bwin[lane >> 1] : 0.f;
  __syncthreads();

  const int rowbase = q * 100;

// cell update: reads pp, bias B; cell regs CREG; emits h pair. All in wave 0.
#define CELL(B, CREG, STORES)                                                 \
    if (lid < 50) {                                                           \
      float2 hp;                                                              \
      _Pragma("unroll")                                                       \
      for (int e = 0; e < 2; ++e) {                                           \
        int cj = 2 * lid + e;                                                 \
        float gI = pp[cj]       + pp[512 + cj] + B[rowbase + cj];             \
        float gF = pp[128 + cj] + pp[640 + cj] + B[400 + rowbase + cj];       \
        float gG = pp[256 + cj] + pp[768 + cj] + B[800 + rowbase + cj];       \
        float gO = pp[384 + cj] + pp[896 + cj] + B[1200 + rowbase + cj];      \
        float cc = sigm(gF) * (e ? CREG.y : CREG.x) + sigm(gI) * tanhf(gG);   \
        if (e) CREG.y = cc; else CREG.x = cc;                                 \
        float h = sigm(gO) * tanhf(cc);                                       \
        if (e) hp.y = h; else hp.x = h;                                       \
      }                                                                       \
      h2 hh = { (_Float16)hp.x, (_Float16)hp.y };                             \
      int gc = rowbase + 2 * lid;                                             \
      STORES                                                                  \
    }

// exchange: wave-0 release fence -> flag store; peers poll relaxed, then
// acquire fence in polling wave, then data loads by the same threads.
#define XCHG(PHOFF, GEN, DESTS)                                               \
    {                                                                         \
      unsigned int gen = (GEN);                                               \
      if (lid == 0) {                                                         \
        __builtin_amdgcn_fence(__ATOMIC_RELEASE, "agent");                    \
        __hip_atomic_store(&flb[q * 16], gen, __ATOMIC_RELAXED,               \
                           __HIP_MEMORY_SCOPE_AGENT);                         \
      }                                                                       \
      if (lid < 150) {                                                        \
        int pi = (lid >= 100) ? 2 : (lid >= 50 ? 1 : 0);                      \
        int i2 = lid - pi * 50;                                               \
        int peer = pi + (pi >= q ? 1 : 0);                                    \
        while (__hip_atomic_load(&flb[peer * 16], __ATOMIC_RELAXED,           \
                                 __HIP_MEMORY_SCOPE_AGENT) < gen)             \
          __builtin_amdgcn_s_sleep(1);                                        \
        __builtin_amdgcn_fence(__ATOMIC_ACQUIRE, "agent");                    \
        unsigned int v = __hip_atomic_load(&xit[(PHOFF) + peer * 64 + i2],    \
                           __ATOMIC_RELAXED, __HIP_MEMORY_SCOPE_AGENT);       \
        h2 hv = toh2(v);                                                      \
        int gc = peer * 100 + 2 * i2;                                         \
        DESTS                                                                 \
      }                                                                       \
    }

  for (int t = 0; t < TT; ++t) {
    // ---- L1 gates ----
    gatesB<NG1>(WL1, svh1, pp, rowbase, lid);
    __syncthreads();
    // ---- L1 cell (+ x(t) staging for L2/L3) ----
    CELL(A.b1, c1,
      soh[gc] = hh.x; soh[gc + 1] = hh.y;
      svh1[80 + gc] = hh.x; svh1[81 + gc] = hh.y;
      svh2[3 + gc]  = hh.x; svh2[4 + gc]  = hh.y;
      __hip_atomic_store(&xit[q * 64 + lid], __builtin_bit_cast(unsigned int, hh),
                         __ATOMIC_RELAXED, __HIP_MEMORY_SCOPE_AGENT);
    )
    if (lid >= 512 && lid < 515) {
      _Float16 xv = (_Float16)A.x[((size_t)item * TT + t) * 3 + (lid - 512)];
      svh2[lid - 512] = xv; svh3[lid - 512] = xv;
    }
    __syncthreads();
    // ---- exchange h1 ----
    XCHG(0, 3u * t + 1u,
      soh[gc] = hv.x; soh[gc + 1] = hv.y;
      svh1[80 + gc] = hv.x; svh1[81 + gc] = hv.y;
      svh2[3 + gc]  = hv.x; svh2[4 + gc]  = hv.y;
    )
    __syncthreads();
    // ---- attention (wave 0, replicated per WG; identical inputs -> identical) ----
    if (wv == 0) {
      const h2* hO = (const h2*)soh;
      float m = 0.f;
      if (lane < 60) {
        const uint4* ww = (const uint4*)WWIN + lane * 25;
        const h2* hp = hO + (lane & 1) * 100;
        float acc = 0.f;
        #pragma unroll 5
        for (int p = 0; p < 25; ++p) {
          uint4 wq = ww[p];
          acc = FDOT2(toh2(wq.x), hp[4 * p + 0], acc);
          acc = FDOT2(toh2(wq.y), hp[4 * p + 1], acc);
          acc = FDOT2(toh2(wq.z), hp[4 * p + 2], acc);
          acc = FDOT2(toh2(wq.w), hp[4 * p + 3], acc);
        }
        m = acc;
      }
      m += __shfl_xor(m, 1);
      float mix = 0.f;
      if (lane < 60 && !(lane & 1)) mix = __expf(m + bwinr);
      float alpha[NK], beta[NK];
      #pragma unroll
      for (int k = 0; k < NK; ++k) {
        alpha[k] = __shfl(mix, 2 * k);
        beta[k]  = __shfl(mix, 20 + 2 * k);
        kapr[k] += __shfl(mix, 40 + 2 * k);
      }
      float u = (float)lane, phi = 0.f;
      #pragma unroll
      for (int k = 0; k < NK; ++k) {
        float d = kapr[k] - u;
        phi += alpha[k] * __expf(-beta[k] * d * d);
      }
      phi *= maskr;
      float w0a = 0.f, w1a = 0.f;
      #pragma unroll 8
      for (int uu2 = 0; uu2 < UU; ++uu2) {
        int   tu = __shfl(textr, uu2);
        float pu = __shfl(phi, uu2);
        w0a += (tu == lane)      ? pu : 0.f;
        w1a += (tu == lane + 64) ? pu : 0.f;
      }
      if (lane < VV) {
        _Float16 wh = (_Float16)w0a;
        svh1[3 + lane] = wh; svh2[403 + lane] = wh; svh3[403 + lane] = wh;
      }
      if (lane + 64 < VV) {
        _Float16 wh = (_Float16)w1a;
        svh1[67 + lane] = wh; svh2[467 + lane] = wh; svh3[467 + lane] = wh;
      }
    }
    __syncthreads();
    // ---- L2 gates ----
    gatesB<NG23>(WL2, svh2, pp, rowbase, lid);
    __syncthreads();
    // ---- L2 cell ----
    CELL(A.b2, c2r,
      soh[400 + gc] = hh.x; soh[401 + gc] = hh.y;
      svh2[480 + gc] = hh.x; svh2[481 + gc] = hh.y;
      svh3[3 + gc]   = hh.x; svh3[4 + gc]   = hh.y;
      __hip_atomic_store(&xit[256 + q * 64 + lid], __builtin_bit_cast(unsigned int, hh),
                         __ATOMIC_RELAXED, __HIP_MEMORY_SCOPE_AGENT);
    )
    __syncthreads();
    // ---- exchange h2 ----
    XCHG(256, 3u * t + 2u,
      soh[400 + gc] = hv.x; soh[401 + gc] = hv.y;
      svh2[480 + gc] = hv.x; svh2[481 + gc] = hv.y;
      svh3[3 + gc]   = hv.x; svh3[4 + gc]   = hv.y;
    )
    __syncthreads();
    // ---- L3 gates ----
    gatesB<NG23>(WL3, svh3, pp, rowbase, lid);
    __syncthreads();
    // ---- L3 cell (+ x(t+1) staging for L1) ----
    CELL(A.b3, c3r,
      soh[800 + gc] = hh.x; soh[801 + gc] = hh.y;
      svh3[480 + gc] = hh.x; svh3[481 + gc] = hh.y;
      __hip_atomic_store(&xit[512 + q * 64 + lid], __builtin_bit_cast(unsigned int, hh),
                         __ATOMIC_RELAXED, __HIP_MEMORY_SCOPE_AGENT);
    )
    if (lid >= 512 && lid < 515 && t + 1 < TT)
      svh1[lid - 512] = (_Float16)A.x[((size_t)item * TT + (t + 1)) * 3 + (lid - 512)];
    __syncthreads();
    // ---- exchange h3 ----
    XCHG(512, 3u * t + 3u,
      soh[800 + gc] = hv.x; soh[801 + gc] = hv.y;
      svh3[480 + gc] = hv.x; svh3[481 + gc] = hv.y;
    )
    __syncthreads();
    // ---- out-proj (rows o = 4*oi + q) ----
    {
      int oi = lid & 31, kp = lid >> 5;
      int base = kp * 18 + (kp < 24 ? kp : 24);
      int cnt  = 18 + (kp < 24 ? 1 : 0);
      const unsigned int* sohu = (const unsigned int*)soh;
      float a = 0.f;
      #pragma unroll 4
      for (int p2 = base; p2 < base + cnt; ++p2)
        a = FDOT2(toh2(WOq[p2 * 32 + oi]), toh2(sohu[p2]), a);
      pO[kp][oi] = a;
    }
    __syncthreads();
    if (lid < 32) {
      int o = 4 * lid + q;
      if (o < NO) {
        float r = A.bout[o];
        #pragma unroll
        for (int k2 = 0; k2 < 32; ++k2) r += pO[k2][lid];
        A.out[((size_t)item * TT + t) * NO + o] = r;
      }
    }
  }
#undef CELL
#undef XCHG
}

extern "C" void kernel_launch(void* const* d_in, const int* in_sizes, int n_in,
                              void* d_out, int out_size, void* d_ws, size_t ws_size,
                              hipStream_t stream) {
  Args a;
  a.x    = (const float*)d_in[0];
  a.text = (const int*)  d_in[1];
  a.mask = (const float*)d_in[2];
  a.Wih1 = (const float*)d_in[3];  a.Whh1 = (const float*)d_in[4];  a.b1 = (const float*)d_in[5];
  a.Wih2 = (const float*)d_in[6];  a.Whh2 = (const float*)d_in[7];  a.b2 = (const float*)d_in[8];
  a.Wih3 = (const float*)d_in[9];  a.Whh3 = (const float*)d_in[10]; a.b3 = (const float*)d_in[11];
  a.Wwin = (const float*)d_in[12]; a.bwin = (const float*)d_in[13];
  a.Wout = (const float*)d_in[14]; a.bout = (const float*)d_in[15];
  a.out  = (float*)d_out;
  a.ws   = (float*)d_ws;
  void* kargs[] = { &a };
  hipLaunchCooperativeKernel((const void*)hsnet_kernel, dim3(NWG), dim3(NTH),
                             kargs, 0, stream);
}

// Round 13
// 39920.990 us; speedup vs baseline: 1.2565x; 1.2565x over previous
//
// Round 13: r12 minus the acquire fences (the only change).
// r12 post-mortem: correct but SLOW -- 9 agent-acquire fences/WG/step = full
// L1+L2 invalidate each, 288 L2 invs/XCD/step -> weights evicted from L2
// continuously, every gate load misses to LLC. The exchange data moves via
// relaxed AGENT-scope atomics which execute at the coherence point (bypass
// L1/L2) -- they need no invalidate. r11's failure was producer-side
// store->flag fabric reordering, fixed by r12's RELEASE fence (kept here:
// vmcnt drain + wbl2-on-clean-L2, cheap). Consumer: poll (atomic load) ->
// program-ordered atomic data loads from the coherence point. No acquire.

#include <hip/hip_runtime.h>
#include <hip/hip_cooperative_groups.h>

namespace cg = cooperative_groups;

#define HH 400
#define NK 10
#define VV 77
#define NO 121
#define TT 600
#define UU 64

#define NWG 256
#define NTH 1024

#define NG1  60     // L1: K=480 -> 60 uint4 groups
#define NG23 110    // L2/L3: K=880

// u32 offsets in ws
#define O_L1  0
#define O_L2  384000
#define O_L3  1088000
#define O_OUT 1792000     // repacked [q][600 kp][32 oi], o = 4*oi+q
#define O_WW  1868800     // Wwin f16: 60 lanes x 100 u32
#define O_XC  1874800     // exchange: [item][phase*256 + q*64 + i], 768/item
#define O_FL  1923952     // flags: [item*64 + q*16]
#define N_END 1928048     // 7.71 MB

typedef _Float16 h2 __attribute__((ext_vector_type(2)));

struct Args {
  const float* __restrict__ x;
  const int*   __restrict__ text;
  const float* __restrict__ mask;
  const float* __restrict__ Wih1; const float* __restrict__ Whh1; const float* __restrict__ b1;
  const float* __restrict__ Wih2; const float* __restrict__ Whh2; const float* __restrict__ b2;
  const float* __restrict__ Wih3; const float* __restrict__ Whh3; const float* __restrict__ b3;
  const float* __restrict__ Wwin; const float* __restrict__ bwin;
  const float* __restrict__ Wout; const float* __restrict__ bout;
  float* __restrict__ out;
  float* __restrict__ ws;
};

__device__ __forceinline__ float sigm(float v) { return 1.0f / (1.0f + __expf(-v)); }

#if defined(__has_builtin)
#if __has_builtin(__builtin_amdgcn_fdot2)
#define FDOT2(a,b,c) __builtin_amdgcn_fdot2((a),(b),(c),false)
#endif
#endif
#ifndef FDOT2
#define FDOT2(a,b,c) fmaf((float)(a).x,(float)(b).x, fmaf((float)(a).y,(float)(b).y,(c)))
#endif

__device__ __forceinline__ h2 toh2(unsigned int u) { return __builtin_bit_cast(h2, u); }

__device__ __forceinline__ float dot4(uint4 p, uint4 v, float a) {
  a = FDOT2(toh2(p.x), toh2(v.x), a);
  a = FDOT2(toh2(p.y), toh2(v.y), a);
  a = FDOT2(toh2(p.z), toh2(v.z), a);
  a = FDOT2(toh2(p.w), toh2(v.w), a);
  return a;
}

__device__ __forceinline__ unsigned int packh2(float f0, float f1) {
  unsigned short lo = __builtin_bit_cast(unsigned short, (_Float16)f0);
  unsigned short hi = __builtin_bit_cast(unsigned short, (_Float16)f1);
  return (unsigned int)lo | ((unsigned int)hi << 16);
}

// Row-band gate matvec: 400 rows (4 gate bands x 100 cells), K split in halves.
template<int NGR>
__device__ __forceinline__ void gatesB(const unsigned int* __restrict__ Wu,
    const _Float16* __restrict__ svh, float* __restrict__ pp, int rowbase, int lid)
{
  int r2 = lid & 127, gi = (lid >> 7) & 3, kh = lid >> 9;
  if (r2 < 100) {
    const uint4* W4 = (const uint4*)Wu + (gi * 400 + rowbase + r2);
    const uint4* vp = (const uint4*)svh;
    constexpr int HG = NGR / 2;
    float a = 0.f;
    #pragma unroll 5
    for (int g = kh * HG; g < kh * HG + HG; ++g)
      a = dot4(W4[(size_t)g * 1600], vp[g], a);
    pp[kh * 512 + gi * 128 + r2] = a;
  }
}

__global__ __launch_bounds__(1024) void hsnet_kernel(Args A) {
  cg::grid_group grid = cg::this_grid();
  const int lid  = threadIdx.x;
  const int bid  = blockIdx.x;
  const int q    = bid >> 6;     // cluster rank 0..3 (row band)
  const int item = bid & 63;
  const int lane = lid & 63;
  const int wv   = lid >> 6;
  unsigned int* __restrict__ wsu = (unsigned int*)A.ws;

  // ===== prologue: weight conversion + zero exchange/flags =====
  for (int i = bid * NTH + lid; i < N_END; i += NWG * NTH) {
    if (i >= O_XC) { wsu[i] = 0u; continue; }
    float f0, f1;
    if (i < O_L2) {
      int u = i, g = u / 6400, rem = u - g * 6400, r = rem >> 2, jj = rem & 3;
      int k0 = 8 * g + 2 * jj;
      if (k0 < 80) { f0 = A.Wih1[r * 80 + k0];       f1 = A.Wih1[r * 80 + k0 + 1]; }
      else         { f0 = A.Whh1[r * 400 + k0 - 80]; f1 = A.Whh1[r * 400 + k0 - 79]; }
    } else if (i < O_L3) {
      int u = i - O_L2, g = u / 6400, rem = u - g * 6400, r = rem >> 2, jj = rem & 3;
      int k0 = 8 * g + 2 * jj;
      if (k0 < 480) { f0 = A.Wih2[r * 480 + k0];        f1 = A.Wih2[r * 480 + k0 + 1]; }
      else          { f0 = A.Whh2[r * 400 + k0 - 480];  f1 = A.Whh2[r * 400 + k0 - 479]; }
    } else if (i < O_OUT) {
      int u = i - O_L3, g = u / 6400, rem = u - g * 6400, r = rem >> 2, jj = rem & 3;
      int k0 = 8 * g + 2 * jj;
      if (k0 < 480) { f0 = A.Wih3[r * 480 + k0];        f1 = A.Wih3[r * 480 + k0 + 1]; }
      else          { f0 = A.Whh3[r * 400 + k0 - 480];  f1 = A.Whh3[r * 400 + k0 - 479]; }
    } else if (i < O_WW) {                   // Wout repack [q4][kp][oi], o=4*oi+q4
      int u = i - O_OUT, q4 = u / 19200, rem = u - q4 * 19200;
      int kp = rem >> 5, oi = rem & 31, o = 4 * oi + q4, k0 = 2 * kp;
      f0 = (o < NO) ? A.Wout[o * 1200 + k0]     : 0.0f;
      f1 = (o < NO) ? A.Wout[o * 1200 + k0 + 1] : 0.0f;
    } else {                                 // Wwin f16: ln=2g+half, 100 u32 each
      int u = i - O_WW, ln = u / 100, p = u - ln * 100;
      int g = ln >> 1, half = ln & 1, k0 = half * 200 + 2 * p;
      f0 = A.Wwin[g * HH + k0]; f1 = A.Wwin[g * HH + k0 + 1];
    }
    wsu[i] = packh2(f0, f1);
  }
  grid.sync();   // sole grid-wide event

  const unsigned int* __restrict__ WL1  = wsu + O_L1;
  const unsigned int* __restrict__ WL2  = wsu + O_L2;
  const unsigned int* __restrict__ WL3  = wsu + O_L3;
  const unsigned int* __restrict__ WOq  = wsu + O_OUT + q * 19200;
  const unsigned int* __restrict__ WWIN = wsu + O_WW;
  unsigned int* xit = wsu + O_XC + item * 768;
  unsigned int* flb = wsu + O_FL + item * 64;

  __shared__ alignas(16) _Float16 svh1[480];   // L1 in: [x3, w77, h1 400]
  __shared__ alignas(16) _Float16 svh2[880];   // L2 in: [x3, h1, w77, h2]
  __shared__ alignas(16) _Float16 svh3[880];   // L3 in: [x3, h2, w77, h3]
  __shared__ alignas(16) _Float16 soh[1200];   // [h1|h2|h3] current step
  __shared__ float pp[1024];                   // gate partials [kh][gi][128]
  __shared__ float pO[32][32];                 // out partials [kp][oi]

  if (lid < 480) svh1[lid] = (_Float16)0.f;
  if (lid < 880) { svh2[lid] = (_Float16)0.f; svh3[lid] = (_Float16)0.f; }
  if (lid < 600) { soh[lid] = (_Float16)0.f; soh[600 + lid] = (_Float16)0.f; }
  if (lid < 3) svh1[lid] = (_Float16)A.x[(size_t)item * TT * 3 + lid];

  float2 c1 = {0.f, 0.f}, c2r = {0.f, 0.f}, c3r = {0.f, 0.f};
  float kapr[NK];
  #pragma unroll
  for (int k = 0; k < NK; ++k) kapr[k] = 0.f;
  float maskr = A.mask[item * UU + lane];
  int   textr = A.text[item * UU + lane];
  float bwinr = (lane < 60 && !(lane & 1)) ? A.bwin[lane >> 1] : 0.f;
  __syncthreads();

  const int rowbase = q * 100;

// cell update: reads pp, bias B; cell regs CREG; emits h pair. All in wave 0.
#define CELL(B, CREG, STORES)                                                 \
    if (lid < 50) {                                                           \
      float2 hp;                                                              \
      _Pragma("unroll")                                                       \
      for (int e = 0; e < 2; ++e) {                                           \
        int cj = 2 * lid + e;                                                 \
        float gI = pp[cj]       + pp[512 + cj] + B[rowbase + cj];             \
        float gF = pp[128 + cj] + pp[640 + cj] + B[400 + rowbase + cj];       \
        float gG = pp[256 + cj] + pp[768 + cj] + B[800 + rowbase + cj];       \
        float gO = pp[384 + cj] + pp[896 + cj] + B[1200 + rowbase + cj];      \
        float cc = sigm(gF) * (e ? CREG.y : CREG.x) + sigm(gI) * tanhf(gG);   \
        if (e) CREG.y = cc; else CREG.x = cc;                                 \
        float h = sigm(gO) * tanhf(cc);                                       \
        if (e) hp.y = h; else hp.x = h;                                       \
      }                                                                       \
      h2 hh = { (_Float16)hp.x, (_Float16)hp.y };                             \
      int gc = rowbase + 2 * lid;                                             \
      STORES                                                                  \
    }

// exchange: wave-0 RELEASE fence (vmcnt drain; data stores were wave-0) ->
// flag store; peers poll relaxed, then program-ordered relaxed atomic data
// loads that execute at the coherence point. NO acquire fence (no L2 inv).
#define XCHG(PHOFF, GEN, DESTS)                                               \
    {                                                                         \
      unsigned int gen = (GEN);                                               \
      if (lid == 0) {                                                         \
        __builtin_amdgcn_fence(__ATOMIC_RELEASE, "agent");                    \
        __hip_atomic_store(&flb[q * 16], gen, __ATOMIC_RELAXED,               \
                           __HIP_MEMORY_SCOPE_AGENT);                         \
      }                                                                       \
      if (lid < 150) {                                                        \
        int pi = (lid >= 100) ? 2 : (lid >= 50 ? 1 : 0);                      \
        int i2 = lid - pi * 50;                                               \
        int peer = pi + (pi >= q ? 1 : 0);                                    \
        while (__hip_atomic_load(&flb[peer * 16], __ATOMIC_RELAXED,           \
                                 __HIP_MEMORY_SCOPE_AGENT) < gen)             \
          __builtin_amdgcn_s_sleep(1);                                        \
        unsigned int v = __hip_atomic_load(&xit[(PHOFF) + peer * 64 + i2],    \
                           __ATOMIC_RELAXED, __HIP_MEMORY_SCOPE_AGENT);       \
        h2 hv = toh2(v);                                                      \
        int gc = peer * 100 + 2 * i2;                                         \
        DESTS                                                                 \
      }                                                                       \
    }

  for (int t = 0; t < TT; ++t) {
    // ---- L1 gates ----
    gatesB<NG1>(WL1, svh1, pp, rowbase, lid);
    __syncthreads();
    // ---- L1 cell (+ x(t) staging for L2/L3) ----
    CELL(A.b1, c1,
      soh[gc] = hh.x; soh[gc + 1] = hh.y;
      svh1[80 + gc] = hh.x; svh1[81 + gc] = hh.y;
      svh2[3 + gc]  = hh.x; svh2[4 + gc]  = hh.y;
      __hip_atomic_store(&xit[q * 64 + lid], __builtin_bit_cast(unsigned int, hh),
                         __ATOMIC_RELAXED, __HIP_MEMORY_SCOPE_AGENT);
    )
    if (lid >= 512 && lid < 515) {
      _Float16 xv = (_Float16)A.x[((size_t)item * TT + t) * 3 + (lid - 512)];
      svh2[lid - 512] = xv; svh3[lid - 512] = xv;
    }
    __syncthreads();
    // ---- exchange h1 ----
    XCHG(0, 3u * t + 1u,
      soh[gc] = hv.x; soh[gc + 1] = hv.y;
      svh1[80 + gc] = hv.x; svh1[81 + gc] = hv.y;
      svh2[3 + gc]  = hv.x; svh2[4 + gc]  = hv.y;
    )
    __syncthreads();
    // ---- attention (wave 0, replicated per WG; identical inputs -> identical) ----
    if (wv == 0) {
      const h2* hO = (const h2*)soh;
      float m = 0.f;
      if (lane < 60) {
        const uint4* ww = (const uint4*)WWIN + lane * 25;
        const h2* hp = hO + (lane & 1) * 100;
        float acc = 0.f;
        #pragma unroll 5
        for (int p = 0; p < 25; ++p) {
          uint4 wq = ww[p];
          acc = FDOT2(toh2(wq.x), hp[4 * p + 0], acc);
          acc = FDOT2(toh2(wq.y), hp[4 * p + 1], acc);
          acc = FDOT2(toh2(wq.z), hp[4 * p + 2], acc);
          acc = FDOT2(toh2(wq.w), hp[4 * p + 3], acc);
        }
        m = acc;
      }
      m += __shfl_xor(m, 1);
      float mix = 0.f;
      if (lane < 60 && !(lane & 1)) mix = __expf(m + bwinr);
      float alpha[NK], beta[NK];
      #pragma unroll
      for (int k = 0; k < NK; ++k) {
        alpha[k] = __shfl(mix, 2 * k);
        beta[k]  = __shfl(mix, 20 + 2 * k);
        kapr[k] += __shfl(mix, 40 + 2 * k);
      }
      float u = (float)lane, phi = 0.f;
      #pragma unroll
      for (int k = 0; k < NK; ++k) {
        float d = kapr[k] - u;
        phi += alpha[k] * __expf(-beta[k] * d * d);
      }
      phi *= maskr;
      float w0a = 0.f, w1a = 0.f;
      #pragma unroll 8
      for (int uu2 = 0; uu2 < UU; ++uu2) {
        int   tu = __shfl(textr, uu2);
        float pu = __shfl(phi, uu2);
        w0a += (tu == lane)      ? pu : 0.f;
        w1a += (tu == lane + 64) ? pu : 0.f;
      }
      if (lane < VV) {
        _Float16 wh = (_Float16)w0a;
        svh1[3 + lane] = wh; svh2[403 + lane] = wh; svh3[403 + lane] = wh;
      }
      if (lane + 64 < VV) {
        _Float16 wh = (_Float16)w1a;
        svh1[67 + lane] = wh; svh2[467 + lane] = wh; svh3[467 + lane] = wh;
      }
    }
    __syncthreads();
    // ---- L2 gates ----
    gatesB<NG23>(WL2, svh2, pp, rowbase, lid);
    __syncthreads();
    // ---- L2 cell ----
    CELL(A.b2, c2r,
      soh[400 + gc] = hh.x; soh[401 + gc] = hh.y;
      svh2[480 + gc] = hh.x; svh2[481 + gc] = hh.y;
      svh3[3 + gc]   = hh.x; svh3[4 + gc]   = hh.y;
      __hip_atomic_store(&xit[256 + q * 64 + lid], __builtin_bit_cast(unsigned int, hh),
                         __ATOMIC_RELAXED, __HIP_MEMORY_SCOPE_AGENT);
    )
    __syncthreads();
    // ---- exchange h2 ----
    XCHG(256, 3u * t + 2u,
      soh[400 + gc] = hv.x; soh[401 + gc] = hv.y;
      svh2[480 + gc] = hv.x; svh2[481 + gc] = hv.y;
      svh3[3 + gc]   = hv.x; svh3[4 + gc]   = hv.y;
    )
    __syncthreads();
    // ---- L3 gates ----
    gatesB<NG23>(WL3, svh3, pp, rowbase, lid);
    __syncthreads();
    // ---- L3 cell (+ x(t+1) staging for L1) ----
    CELL(A.b3, c3r,
      soh[800 + gc] = hh.x; soh[801 + gc] = hh.y;
      svh3[480 + gc] = hh.x; svh3[481 + gc] = hh.y;
      __hip_atomic_store(&xit[512 + q * 64 + lid], __builtin_bit_cast(unsigned int, hh),
                         __ATOMIC_RELAXED, __HIP_MEMORY_SCOPE_AGENT);
    )
    if (lid >= 512 && lid < 515 && t + 1 < TT)
      svh1[lid - 512] = (_Float16)A.x[((size_t)item * TT + (t + 1)) * 3 + (lid - 512)];
    __syncthreads();
    // ---- exchange h3 ----
    XCHG(512, 3u * t + 3u,
      soh[800 + gc] = hv.x; soh[801 + gc] = hv.y;
      svh3[480 + gc] = hv.x; svh3[481 + gc] = hv.y;
    )
    __syncthreads();
    // ---- out-proj (rows o = 4*oi + q) ----
    {
      int oi = lid & 31, kp = lid >> 5;
      int base = kp * 18 + (kp < 24 ? kp : 24);
      int cnt  = 18 + (kp < 24 ? 1 : 0);
      const unsigned int* sohu = (const unsigned int*)soh;
      float a = 0.f;
      #pragma unroll 4
      for (int p2 = base; p2 < base + cnt; ++p2)
        a = FDOT2(toh2(WOq[p2 * 32 + oi]), toh2(sohu[p2]), a);
      pO[kp][oi] = a;
    }
    __syncthreads();
    if (lid < 32) {
      int o = 4 * lid + q;
      if (o < NO) {
        float r = A.bout[o];
        #pragma unroll
        for (int k2 = 0; k2 < 32; ++k2) r += pO[k2][lid];
        A.out[((size_t)item * TT + t) * NO + o] = r;
      }
    }
  }
#undef CELL
#undef XCHG
}

extern "C" void kernel_launch(void* const* d_in, const int* in_sizes, int n_in,
                              void* d_out, int out_size, void* d_ws, size_t ws_size,
                              hipStream_t stream) {
  Args a;
  a.x    = (const float*)d_in[0];
  a.text = (const int*)  d_in[1];
  a.mask = (const float*)d_in[2];
  a.Wih1 = (const float*)d_in[3];  a.Whh1 = (const float*)d_in[4];  a.b1 = (const float*)d_in[5];
  a.Wih2 = (const float*)d_in[6];  a.Whh2 = (const float*)d_in[7];  a.b2 = (const float*)d_in[8];
  a.Wih3 = (const float*)d_in[9];  a.Whh3 = (const float*)d_in[10]; a.b3 = (const float*)d_in[11];
  a.Wwin = (const float*)d_in[12]; a.bwin = (const float*)d_in[13];
  a.Wout = (const float*)d_in[14]; a.bout = (const float*)d_in[15];
  a.out  = (float*)d_out;
  a.ws   = (float*)d_ws;
  void* kargs[] = { &a };
  hipLaunchCooperativeKernel((const void*)hsnet_kernel, dim3(NWG), dim3(NTH),
                             kargs, 0, stream);
}

// Round 14
// 19633.353 us; speedup vs baseline: 2.5549x; 2.0333x over previous
//
// Round 14: fence-free tag-in-word exchange + band-per-XCD placement.
// r13: stable 66.5us/step; remaining costs = 3 wbl2-fences/WG/step (L2
// writeback scans on the exchange critical path) + 50% L2-miss weight stream
// (each XCD needed all 4 bands = 7.5MB > 4MB L2).
// Fix A: exchange word = u64 {gen<<32 | h2pair}, one relaxed agent atomic
//   store; consumer polls the SAME word until gen matches (per-address
//   coherence = ordering). No fences/flags/wbl2/inv anywhere in the loop.
// Fix B: bid remap so bid%8 = 2q+(item&1): each XCD hosts ONE row-band ->
//   ~2MB weight set fits L2 -> gate loads become L2 hits.
// Fix C: out-proj h1|h2 part computed before h3 poll; out-write folded into
//   next step's gates phase. 8 syncs/step.

#include <hip/hip_runtime.h>
#include <hip/hip_cooperative_groups.h>

namespace cg = cooperative_groups;

#define HH 400
#define NK 10
#define VV 77
#define NO 121
#define TT 600
#define UU 64

#define NWG 256
#define NTH 1024

#define NG1  60     // L1: K=480 -> 60 uint4 groups
#define NG23 110    // L2/L3: K=880

// u32 offsets in ws
#define O_L1  0
#define O_L2  384000
#define O_L3  1088000
#define O_OUT 1792000     // repacked [q][600 kp][32 oi], o = 4*oi+q
#define O_WW  1868800     // Wwin f16: 60 lanes x 100 u32
#define O_XC  1874800     // exchange u64 region: [item][ph*256 + q*64 + i]

typedef _Float16 h2 __attribute__((ext_vector_type(2)));

struct Args {
  const float* __restrict__ x;
  const int*   __restrict__ text;
  const float* __restrict__ mask;
  const float* __restrict__ Wih1; const float* __restrict__ Whh1; const float* __restrict__ b1;
  const float* __restrict__ Wih2; const float* __restrict__ Whh2; const float* __restrict__ b2;
  const float* __restrict__ Wih3; const float* __restrict__ Whh3; const float* __restrict__ b3;
  const float* __restrict__ Wwin; const float* __restrict__ bwin;
  const float* __restrict__ Wout; const float* __restrict__ bout;
  float* __restrict__ out;
  float* __restrict__ ws;
};

__device__ __forceinline__ float sigm(float v) { return 1.0f / (1.0f + __expf(-v)); }

#if defined(__has_builtin)
#if __has_builtin(__builtin_amdgcn_fdot2)
#define FDOT2(a,b,c) __builtin_amdgcn_fdot2((a),(b),(c),false)
#endif
#endif
#ifndef FDOT2
#define FDOT2(a,b,c) fmaf((float)(a).x,(float)(b).x, fmaf((float)(a).y,(float)(b).y,(c)))
#endif

__device__ __forceinline__ h2 toh2(unsigned int u) { return __builtin_bit_cast(h2, u); }

__device__ __forceinline__ float dot4(uint4 p, uint4 v, float a) {
  a = FDOT2(toh2(p.x), toh2(v.x), a);
  a = FDOT2(toh2(p.y), toh2(v.y), a);
  a = FDOT2(toh2(p.z), toh2(v.z), a);
  a = FDOT2(toh2(p.w), toh2(v.w), a);
  return a;
}

__device__ __forceinline__ unsigned int packh2(float f0, float f1) {
  unsigned short lo = __builtin_bit_cast(unsigned short, (_Float16)f0);
  unsigned short hi = __builtin_bit_cast(unsigned short, (_Float16)f1);
  return (unsigned int)lo | ((unsigned int)hi << 16);
}

// Row-band gate matvec: 400 rows (4 gate bands x 100 cells), K split in halves.
template<int NGR>
__device__ __forceinline__ void gatesB(const unsigned int* __restrict__ Wu,
    const _Float16* __restrict__ svh, float* __restrict__ pp, int rowbase, int lid)
{
  int r2 = lid & 127, gi = (lid >> 7) & 3, kh = lid >> 9;
  if (r2 < 100) {
    const uint4* W4 = (const uint4*)Wu + (gi * 400 + rowbase + r2);
    const uint4* vp = (const uint4*)svh;
    constexpr int HG = NGR / 2;
    float a = 0.f;
    #pragma unroll 5
    for (int g = kh * HG; g < kh * HG + HG; ++g)
      a = dot4(W4[(size_t)g * 1600], vp[g], a);
    pp[kh * 512 + gi * 128 + r2] = a;
  }
}

__global__ __launch_bounds__(1024) void hsnet_kernel(Args A) {
  cg::grid_group grid = cg::this_grid();
  const int lid  = threadIdx.x;
  const int bid  = blockIdx.x;
  // band-per-XCD mapping: bid = 8*(item>>1) + 2q + (item&1)
  const int q    = (bid & 7) >> 1;               // row band 0..3
  const int item = (bid & 1) | ((bid >> 3) << 1);
  const int lane = lid & 63;
  const int wv   = lid >> 6;
  unsigned int* __restrict__ wsu = (unsigned int*)A.ws;

  // ===== prologue: weight conversion + zero exchange words =====
  for (int i = bid * NTH + lid; i < O_XC; i += NWG * NTH) {
    float f0, f1;
    if (i < O_L2) {
      int u = i, g = u / 6400, rem = u - g * 6400, r = rem >> 2, jj = rem & 3;
      int k0 = 8 * g + 2 * jj;
      if (k0 < 80) { f0 = A.Wih1[r * 80 + k0];       f1 = A.Wih1[r * 80 + k0 + 1]; }
      else         { f0 = A.Whh1[r * 400 + k0 - 80]; f1 = A.Whh1[r * 400 + k0 - 79]; }
    } else if (i < O_L3) {
      int u = i - O_L2, g = u / 6400, rem = u - g * 6400, r = rem >> 2, jj = rem & 3;
      int k0 = 8 * g + 2 * jj;
      if (k0 < 480) { f0 = A.Wih2[r * 480 + k0];        f1 = A.Wih2[r * 480 + k0 + 1]; }
      else          { f0 = A.Whh2[r * 400 + k0 - 480];  f1 = A.Whh2[r * 400 + k0 - 479]; }
    } else if (i < O_OUT) {
      int u = i - O_L3, g = u / 6400, rem = u - g * 6400, r = rem >> 2, jj = rem & 3;
      int k0 = 8 * g + 2 * jj;
      if (k0 < 480) { f0 = A.Wih3[r * 480 + k0];        f1 = A.Wih3[r * 480 + k0 + 1]; }
      else          { f0 = A.Whh3[r * 400 + k0 - 480];  f1 = A.Whh3[r * 400 + k0 - 479]; }
    } else if (i < O_WW) {                   // Wout repack [q4][kp][oi], o=4*oi+q4
      int u = i - O_OUT, q4 = u / 19200, rem = u - q4 * 19200;
      int kp = rem >> 5, oi = rem & 31, o = 4 * oi + q4, k0 = 2 * kp;
      f0 = (o < NO) ? A.Wout[o * 1200 + k0]     : 0.0f;
      f1 = (o < NO) ? A.Wout[o * 1200 + k0 + 1] : 0.0f;
    } else {                                 // Wwin f16: ln=2g+half, 100 u32 each
      int u = i - O_WW, ln = u / 100, p = u - ln * 100;
      int g = ln >> 1, half = ln & 1, k0 = half * 200 + 2 * p;
      f0 = A.Wwin[g * HH + k0]; f1 = A.Wwin[g * HH + k0 + 1];
    }
    wsu[i] = packh2(f0, f1);
  }
  {
    unsigned long long* xz = (unsigned long long*)(wsu + O_XC);
    for (int i = bid * NTH + lid; i < 64 * 768; i += NWG * NTH)
      __hip_atomic_store(&xz[i], 0ull, __ATOMIC_RELAXED, __HIP_MEMORY_SCOPE_AGENT);
  }
  grid.sync();   // sole grid-wide event

  const unsigned int* __restrict__ WL1  = wsu + O_L1;
  const unsigned int* __restrict__ WL2  = wsu + O_L2;
  const unsigned int* __restrict__ WL3  = wsu + O_L3;
  const unsigned int* __restrict__ WOq  = wsu + O_OUT + q * 19200;
  const unsigned int* __restrict__ WWIN = wsu + O_WW;
  unsigned long long* xit = (unsigned long long*)(wsu + O_XC) + (size_t)item * 768;

  __shared__ alignas(16) _Float16 svh1[480];   // L1 in: [x3, w77, h1 400]
  __shared__ alignas(16) _Float16 svh2[880];   // L2 in: [x3, h1, w77, h2]
  __shared__ alignas(16) _Float16 svh3[880];   // L3 in: [x3, h2, w77, h3]
  __shared__ alignas(16) _Float16 soh[1200];   // [h1|h2|h3] current step
  __shared__ float pp[1024];                   // gate partials [kh][gi][128]
  __shared__ float pO[32][32];                 // out partials [kp][oi]

  if (lid < 480) svh1[lid] = (_Float16)0.f;
  if (lid < 880) { svh2[lid] = (_Float16)0.f; svh3[lid] = (_Float16)0.f; }
  if (lid < 600) { soh[lid] = (_Float16)0.f; soh[600 + lid] = (_Float16)0.f; }
  if (lid < 3) svh1[lid] = (_Float16)A.x[(size_t)item * TT * 3 + lid];

  float2 c1 = {0.f, 0.f}, c2r = {0.f, 0.f}, c3r = {0.f, 0.f};
  float kapr[NK];
  #pragma unroll
  for (int k = 0; k < NK; ++k) kapr[k] = 0.f;
  float maskr = A.mask[item * UU + lane];
  int   textr = A.text[item * UU + lane];
  float bwinr = (lane < 60 && !(lane & 1)) ? A.bwin[lane >> 1] : 0.f;
  __syncthreads();

  const int rowbase = q * 100;

// cell update (wave 0, lid<50): reads pp, bias B; emits h2 pair + tagged u64
#define CELL(B, CREG, PH, GEN, STORES)                                        \
    if (lid < 50) {                                                           \
      float2 hp;                                                              \
      _Pragma("unroll")                                                       \
      for (int e = 0; e < 2; ++e) {                                           \
        int cj = 2 * lid + e;                                                 \
        float gI = pp[cj]       + pp[512 + cj] + B[rowbase + cj];             \
        float gF = pp[128 + cj] + pp[640 + cj] + B[400 + rowbase + cj];       \
        float gG = pp[256 + cj] + pp[768 + cj] + B[800 + rowbase + cj];       \
        float gO = pp[384 + cj] + pp[896 + cj] + B[1200 + rowbase + cj];      \
        float cc = sigm(gF) * (e ? CREG.y : CREG.x) + sigm(gI) * tanhf(gG);   \
        if (e) CREG.y = cc; else CREG.x = cc;                                 \
        float h = sigm(gO) * tanhf(cc);                                       \
        if (e) hp.y = h; else hp.x = h;                                       \
      }                                                                       \
      h2 hh = { (_Float16)hp.x, (_Float16)hp.y };                             \
      int gc = rowbase + 2 * lid;                                             \
      unsigned long long tw = ((unsigned long long)(GEN) << 32)               \
                            | (unsigned long long)__builtin_bit_cast(unsigned int, hh); \
      __hip_atomic_store(&xit[(PH) * 256 + q * 64 + lid], tw,                 \
                         __ATOMIC_RELAXED, __HIP_MEMORY_SCOPE_AGENT);         \
      STORES                                                                  \
    }

// poll peers' tagged words (150 threads); per-address coherence orders data
#define POLL(PH, GEN, DESTS)                                                  \
    if (lid < 150) {                                                          \
      int pi = (lid >= 100) ? 2 : (lid >= 50 ? 1 : 0);                        \
      int i2 = lid - pi * 50;                                                 \
      int peer = pi + (pi >= q ? 1 : 0);                                      \
      const unsigned int gexp = (GEN);                                        \
      unsigned long long v64;                                                 \
      while ((unsigned int)((v64 = __hip_atomic_load(                         \
                 &xit[(PH) * 256 + peer * 64 + i2],                           \
                 __ATOMIC_RELAXED, __HIP_MEMORY_SCOPE_AGENT)) >> 32) != gexp) \
        __builtin_amdgcn_s_sleep(1);                                          \
      h2 hv = toh2((unsigned int)v64);                                        \
      int gc = peer * 100 + 2 * i2;                                           \
      DESTS                                                                   \
    }

  for (int t = 0; t < TT; ++t) {
    // -- phase 1: L1 gates (+ folded out-write for t-1) --
    if (t > 0 && lid < 32) {
      int o = 4 * lid + q;
      if (o < NO) {
        float r = A.bout[o];
        #pragma unroll
        for (int k2 = 0; k2 < 32; ++k2) r += pO[k2][lid];
        A.out[((size_t)item * TT + (t - 1)) * NO + o] = r;
      }
    }
    gatesB<NG1>(WL1, svh1, pp, rowbase, lid);
    __syncthreads();
    // -- phase 2: L1 cell + x(t) staging + poll h1 --
    CELL(A.b1, c1, 0, 3u * t + 1u,
      soh[gc] = hh.x; soh[gc + 1] = hh.y;
      svh1[80 + gc] = hh.x; svh1[81 + gc] = hh.y;
      svh2[3 + gc]  = hh.x; svh2[4 + gc]  = hh.y;
    )
    if (lid >= 512 && lid < 515) {
      _Float16 xv = (_Float16)A.x[((size_t)item * TT + t) * 3 + (lid - 512)];
      svh2[lid - 512] = xv; svh3[lid - 512] = xv;
    }
    POLL(0, 3u * t + 1u,
      soh[gc] = hv.x; soh[gc + 1] = hv.y;
      svh1[80 + gc] = hv.x; svh1[81 + gc] = hv.y;
      svh2[3 + gc]  = hv.x; svh2[4 + gc]  = hv.y;
    )
    __syncthreads();
    // -- phase 3: attention (wave 0, replicated; bit-identical inputs) --
    if (wv == 0) {
      const h2* hO = (const h2*)soh;
      float m = 0.f;
      if (lane < 60) {
        const uint4* ww = (const uint4*)WWIN + lane * 25;
        const h2* hp = hO + (lane & 1) * 100;
        float acc = 0.f;
        #pragma unroll 5
        for (int p = 0; p < 25; ++p) {
          uint4 wq = ww[p];
          acc = FDOT2(toh2(wq.x), hp[4 * p + 0], acc);
          acc = FDOT2(toh2(wq.y), hp[4 * p + 1], acc);
          acc = FDOT2(toh2(wq.z), hp[4 * p + 2], acc);
          acc = FDOT2(toh2(wq.w), hp[4 * p + 3], acc);
        }
        m = acc;
      }
      m += __shfl_xor(m, 1);
      float mix = 0.f;
      if (lane < 60 && !(lane & 1)) mix = __expf(m + bwinr);
      float alpha[NK], beta[NK];
      #pragma unroll
      for (int k = 0; k < NK; ++k) {
        alpha[k] = __shfl(mix, 2 * k);
        beta[k]  = __shfl(mix, 20 + 2 * k);
        kapr[k] += __shfl(mix, 40 + 2 * k);
      }
      float u = (float)lane, phi = 0.f;
      #pragma unroll
      for (int k = 0; k < NK; ++k) {
        float d = kapr[k] - u;
        phi += alpha[k] * __expf(-beta[k] * d * d);
      }
      phi *= maskr;
      float w0a = 0.f, w1a = 0.f;
      #pragma unroll 8
      for (int uu2 = 0; uu2 < UU; ++uu2) {
        int   tu = __shfl(textr, uu2);
        float pu = __shfl(phi, uu2);
        w0a += (tu == lane)      ? pu : 0.f;
        w1a += (tu == lane + 64) ? pu : 0.f;
      }
      if (lane < VV) {
        _Float16 wh = (_Float16)w0a;
        svh1[3 + lane] = wh; svh2[403 + lane] = wh; svh3[403 + lane] = wh;
      }
      if (lane + 64 < VV) {
        _Float16 wh = (_Float16)w1a;
        svh1[67 + lane] = wh; svh2[467 + lane] = wh; svh3[467 + lane] = wh;
      }
    }
    __syncthreads();
    // -- phase 4: L2 gates --
    gatesB<NG23>(WL2, svh2, pp, rowbase, lid);
    __syncthreads();
    // -- phase 5: L2 cell + poll h2 --
    CELL(A.b2, c2r, 1, 3u * t + 2u,
      soh[400 + gc] = hh.x; soh[401 + gc] = hh.y;
      svh2[480 + gc] = hh.x; svh2[481 + gc] = hh.y;
      svh3[3 + gc]   = hh.x; svh3[4 + gc]   = hh.y;
    )
    POLL(1, 3u * t + 2u,
      soh[400 + gc] = hv.x; soh[401 + gc] = hv.y;
      svh2[480 + gc] = hv.x; svh2[481 + gc] = hv.y;
      svh3[3 + gc]   = hv.x; svh3[4 + gc]   = hv.y;
    )
    __syncthreads();
    // -- phase 6: L3 gates --
    gatesB<NG23>(WL3, svh3, pp, rowbase, lid);
    __syncthreads();
    // -- phase 7: L3 cell + out partial (h1|h2) + poll h3 --
    CELL(A.b3, c3r, 2, 3u * t + 3u,
      soh[800 + gc] = hh.x; soh[801 + gc] = hh.y;
      svh3[480 + gc] = hh.x; svh3[481 + gc] = hh.y;
    )
    float oacc;
    {
      int oi = lid & 31, kc = lid >> 5;
      int base = kc * 12 + (kc < 16 ? kc : 16);
      int cnt  = 12 + (kc < 16 ? 1 : 0);
      const unsigned int* sohu = (const unsigned int*)soh;
      float a = 0.f;
      #pragma unroll 4
      for (int p2 = base; p2 < base + cnt; ++p2)
        a = FDOT2(toh2(WOq[p2 * 32 + oi]), toh2(sohu[p2]), a);
      oacc = a;
    }
    if (lid >= 512 && lid < 515 && t + 1 < TT)
      svh1[lid - 512] = (_Float16)A.x[((size_t)item * TT + (t + 1)) * 3 + (lid - 512)];
    POLL(2, 3u * t + 3u,
      soh[800 + gc] = hv.x; soh[801 + gc] = hv.y;
      svh3[480 + gc] = hv.x; svh3[481 + gc] = hv.y;
    )
    __syncthreads();
    // -- phase 8: out partial (h3) + pO store --
    {
      int oi = lid & 31, kc = lid >> 5;
      int base = 400 + kc * 6 + (kc < 8 ? kc : 8);
      int cnt  = 6 + (kc < 8 ? 1 : 0);
      const unsigned int* sohu = (const unsigned int*)soh;
      float a = oacc;
      #pragma unroll 4
      for (int p2 = base; p2 < base + cnt; ++p2)
        a = FDOT2(toh2(WOq[p2 * 32 + oi]), toh2(sohu[p2]), a);
      pO[kc][oi] = a;
    }
    __syncthreads();
  }
  // epilogue: out-write for t=599
  if (lid < 32) {
    int o = 4 * lid + q;
    if (o < NO) {
      float r = A.bout[o];
      #pragma unroll
      for (int k2 = 0; k2 < 32; ++k2) r += pO[k2][lid];
      A.out[((size_t)item * TT + 599) * NO + o] = r;
    }
  }
#undef CELL
#undef POLL
}

extern "C" void kernel_launch(void* const* d_in, const int* in_sizes, int n_in,
                              void* d_out, int out_size, void* d_ws, size_t ws_size,
                              hipStream_t stream) {
  Args a;
  a.x    = (const float*)d_in[0];
  a.text = (const int*)  d_in[1];
  a.mask = (const float*)d_in[2];
  a.Wih1 = (const float*)d_in[3];  a.Whh1 = (const float*)d_in[4];  a.b1 = (const float*)d_in[5];
  a.Wih2 = (const float*)d_in[6];  a.Whh2 = (const float*)d_in[7];  a.b2 = (const float*)d_in[8];
  a.Wih3 = (const float*)d_in[9];  a.Whh3 = (const float*)d_in[10]; a.b3 = (const float*)d_in[11];
  a.Wwin = (const float*)d_in[12]; a.bwin = (const float*)d_in[13];
  a.Wout = (const float*)d_in[14]; a.bout = (const float*)d_in[15];
  a.out  = (float*)d_out;
  a.ws   = (float*)d_ws;
  void* kargs[] = { &a };
  hipLaunchCooperativeKernel((const void*)hsnet_kernel, dim3(NWG), dim3(NTH),
                             kargs, 0, stream);
}

// Round 15
// 16482.843 us; speedup vs baseline: 3.0432x; 1.1911x over previous
//
// Round 15: 2 items/WG x 8 bands — halve the per-CU L2 weight stream.
// r14 closed at the L2->CU BW wall: 32 WGs/XCD x 1.87MB/step = 14us/step.
// Now WG=(band 8, group 32): 50 cells, FULL K, items {2g,2g+1}; thread =
// (row 200, kslice 5) = 1000 threads; each weight uint4 loaded once, dotted
// vs both items (replication 64->32, 0.94MB/CU/step). No cross-WG K-split ->
// no new hops. Tagged-u64 exchange (7 peers), band-per-XCD, 8 syncs/step,
// wave-0/1 attention — all r14-proven machinery.

#include <hip/hip_runtime.h>
#include <hip/hip_cooperative_groups.h>

namespace cg = cooperative_groups;

#define HH 400
#define NK 10
#define VV 77
#define NO 121
#define TT 600
#define UU 64

#define NWG 256
#define NTH 1024

#define KS  5      // K-slices per WG (within-WG, LDS-reduced)
#define J1  12     // L1: K=480 halfs = 5 x 96 = 5 x 12 uint4
#define J23 22     // L2/L3: K=880 = 5 x 176 = 5 x 22 uint4
#define JO  30     // out: K=1200 = 5 x 240 = 5 x 30 uint4

// u32 offsets in ws
#define O_L1  0          // 8*5*12*200 uint4 = 384000 u32
#define O_L2  384000     // 8*5*22*200 uint4 = 704000 u32
#define O_L3  1088000
#define O_OUT 1792000    // 8*5*30*16 uint4 = 76800 u32
#define O_WW  1868800    // Wwin f16: 6000 u32
#define O_XC  1874800    // exchange: 32 groups x 1200 u64

typedef _Float16 h2 __attribute__((ext_vector_type(2)));

struct Args {
  const float* __restrict__ x;
  const int*   __restrict__ text;
  const float* __restrict__ mask;
  const float* __restrict__ Wih1; const float* __restrict__ Whh1; const float* __restrict__ b1;
  const float* __restrict__ Wih2; const float* __restrict__ Whh2; const float* __restrict__ b2;
  const float* __restrict__ Wih3; const float* __restrict__ Whh3; const float* __restrict__ b3;
  const float* __restrict__ Wwin; const float* __restrict__ bwin;
  const float* __restrict__ Wout; const float* __restrict__ bout;
  float* __restrict__ out;
  float* __restrict__ ws;
};

__device__ __forceinline__ float sigm(float v) { return 1.0f / (1.0f + __expf(-v)); }

#if defined(__has_builtin)
#if __has_builtin(__builtin_amdgcn_fdot2)
#define FDOT2(a,b,c) __builtin_amdgcn_fdot2((a),(b),(c),false)
#endif
#endif
#ifndef FDOT2
#define FDOT2(a,b,c) fmaf((float)(a).x,(float)(b).x, fmaf((float)(a).y,(float)(b).y,(c)))
#endif

__device__ __forceinline__ h2 toh2(unsigned int u) { return __builtin_bit_cast(h2, u); }

__device__ __forceinline__ float dot4(uint4 p, uint4 v, float a) {
  a = FDOT2(toh2(p.x), toh2(v.x), a);
  a = FDOT2(toh2(p.y), toh2(v.y), a);
  a = FDOT2(toh2(p.z), toh2(v.z), a);
  a = FDOT2(toh2(p.w), toh2(v.w), a);
  return a;
}

__device__ __forceinline__ unsigned int packh2(float f0, float f1) {
  unsigned short lo = __builtin_bit_cast(unsigned short, (_Float16)f0);
  unsigned short hi = __builtin_bit_cast(unsigned short, (_Float16)f1);
  return (unsigned int)lo | ((unsigned int)hi << 16);
}

__global__ __launch_bounds__(1024) void hsnet_kernel(Args A) {
  cg::grid_group grid = cg::this_grid();
  const int lid  = threadIdx.x;
  const int bid  = blockIdx.x;
  const int band = bid & 7;        // one band per XCD
  const int grp  = bid >> 3;       // 0..31: items {2g, 2g+1}
  const int lane = lid & 63;
  const int wv   = lid >> 6;
  unsigned int* __restrict__ wsu = (unsigned int*)A.ws;

  // ===== prologue: weight repack [band][s][j][row/o] + zero exchange =====
  for (int i = bid * NTH + lid; i < O_XC; i += NWG * NTH) {
    float f0, f1;
    if (i < O_OUT) {
      const float *Wih, *Whh; int J, LD, rel;
      if (i < O_L2)      { rel = i;          J = J1;  LD = 80;  Wih = A.Wih1; Whh = A.Whh1; }
      else if (i < O_L3) { rel = i - O_L2;   J = J23; LD = 480; Wih = A.Wih2; Whh = A.Whh2; }
      else               { rel = i - O_L3;   J = J23; LD = 480; Wih = A.Wih3; Whh = A.Whh3; }
      int U = rel >> 2, c4 = rel & 3;
      int r = U % 200, T = U / 200;
      int j = T % J,  T2 = T / J;
      int s = T2 % KS, b = T2 / KS;
      int cell = b * 50 + (r % 50), gate = r / 50;
      int grow = gate * 400 + cell;
      int kk = (s * J + j) * 8 + 2 * c4;
      if (kk < LD) { f0 = Wih[grow * LD + kk];        f1 = Wih[grow * LD + kk + 1]; }
      else         { f0 = Whh[grow * 400 + kk - LD];  f1 = Whh[grow * 400 + kk - LD + 1]; }
    } else if (i < O_WW) {
      int rel = i - O_OUT;
      int U = rel >> 2, c4 = rel & 3;
      int o16 = U % 16, T = U / 16;
      int j = T % JO, T2 = T / JO;
      int s = T2 % KS, b = T2 / KS;
      int oglob = 8 * o16 + b;
      int kk = (s * JO + j) * 8 + 2 * c4;
      f0 = (oglob < NO) ? A.Wout[oglob * 1200 + kk]     : 0.f;
      f1 = (oglob < NO) ? A.Wout[oglob * 1200 + kk + 1] : 0.f;
    } else {
      int u = i - O_WW, ln = u / 100, p = u - ln * 100;
      int gw = ln >> 1, half = ln & 1, k0 = half * 200 + 2 * p;
      f0 = A.Wwin[gw * HH + k0]; f1 = A.Wwin[gw * HH + k0 + 1];
    }
    wsu[i] = packh2(f0, f1);
  }
  {
    unsigned long long* xz = (unsigned long long*)(wsu + O_XC);
    for (int i = bid * NTH + lid; i < 32 * 1200; i += NWG * NTH)
      __hip_atomic_store(&xz[i], 0ull, __ATOMIC_RELAXED, __HIP_MEMORY_SCOPE_AGENT);
  }
  grid.sync();   // sole grid-wide event

  const uint4* W1b = (const uint4*)(wsu + O_L1)  + (size_t)band * KS * J1  * 200;
  const uint4* W2b = (const uint4*)(wsu + O_L2)  + (size_t)band * KS * J23 * 200;
  const uint4* W3b = (const uint4*)(wsu + O_L3)  + (size_t)band * KS * J23 * 200;
  const uint4* WOb = (const uint4*)(wsu + O_OUT) + (size_t)band * KS * JO  * 16;
  const unsigned int* __restrict__ WWIN = wsu + O_WW;
  unsigned long long* xg = (unsigned long long*)(wsu + O_XC) + (size_t)grp * 1200;

  __shared__ alignas(16) _Float16 svh1[2][480];   // L1 in: [x3,w77,h1 400]
  __shared__ alignas(16) _Float16 svh2[2][880];   // L2 in: [x3,h1,w77,h2]
  __shared__ alignas(16) _Float16 svh3[2][880];   // L3 in: [x3,h2,w77,h3]
  __shared__ alignas(16) _Float16 soh[2][1200];   // [h1|h2|h3]
  __shared__ float pp[2000];                      // [s][il][row 200]
  __shared__ float pO[160];                       // [s][il][oi 16]

  for (int i = lid; i < 960;  i += NTH) (&svh1[0][0])[i] = (_Float16)0.f;
  for (int i = lid; i < 1760; i += NTH) { (&svh2[0][0])[i] = (_Float16)0.f;
                                          (&svh3[0][0])[i] = (_Float16)0.f; }
  for (int i = lid; i < 2400; i += NTH) (&soh[0][0])[i] = (_Float16)0.f;
  if (lid >= 512 && lid < 518) {
    int il = (lid - 512) / 3, cm = (lid - 512) % 3;
    svh1[il][cm] = (_Float16)A.x[(size_t)(2 * grp + il) * TT * 3 + cm];
  }

  const int rg = lid % 200;
  const int sg = lid / 200;   // kslice, active < 5
  const int itm = 2 * grp + ((wv < 2) ? wv : 0);
  float maskr = A.mask[itm * UU + lane];
  int   textr = A.text[itm * UU + lane];
  float bwinr = (lane < 60 && !(lane & 1)) ? A.bwin[lane >> 1] : 0.f;
  float kapr[NK];
  #pragma unroll
  for (int k = 0; k < NK; ++k) kapr[k] = 0.f;
  float2 c1 = {0.f, 0.f}, c2r = {0.f, 0.f}, c3r = {0.f, 0.f};
  __syncthreads();

// gate matvec: thread (rg, sg) loads weight uint4 once, dots vs both items
#define GATES(WB, J, V0, V1)                                                  \
    if (sg < KS) {                                                            \
      const uint4* Wp = (WB) + (size_t)(sg * (J)) * 200 + rg;                 \
      const uint4* p0 = (const uint4*)((V0) + sg * (J) * 8);                  \
      const uint4* p1 = (const uint4*)((V1) + sg * (J) * 8);                  \
      float a0 = 0.f, a1 = 0.f;                                               \
      _Pragma("unroll 2")                                                     \
      for (int j = 0; j < (J); ++j) {                                         \
        uint4 w = Wp[(size_t)j * 200];                                        \
        a0 = dot4(w, p0[j], a0); a1 = dot4(w, p1[j], a1);                     \
      }                                                                       \
      pp[(sg * 2 + 0) * 200 + rg] = a0;                                       \
      pp[(sg * 2 + 1) * 200 + rg] = a1;                                       \
    }

// cell update: lid<50 -> (il=lid/25, pr=lid%25), cells {2pr,2pr+1} of item il
#define CELL(B, CREG, PH, GEN, STORES)                                        \
    if (lid < 50) {                                                           \
      int il = lid / 25, pr = lid % 25;                                       \
      float2 hp;                                                              \
      _Pragma("unroll")                                                       \
      for (int e = 0; e < 2; ++e) {                                           \
        int cl = 2 * pr + e;                                                  \
        float gI = 0.f, gF = 0.f, gG = 0.f, gO = 0.f;                         \
        _Pragma("unroll")                                                     \
        for (int s = 0; s < KS; ++s) {                                        \
          const float* b0 = &pp[(s * 2 + il) * 200];                          \
          gI += b0[cl]; gF += b0[50 + cl]; gG += b0[100 + cl]; gO += b0[150 + cl]; \
        }                                                                     \
        int gcell = band * 50 + cl;                                           \
        gI += B[gcell]; gF += B[400 + gcell]; gG += B[800 + gcell]; gO += B[1200 + gcell]; \
        float cc = sigm(gF) * (e ? CREG.y : CREG.x) + sigm(gI) * tanhf(gG);   \
        if (e) CREG.y = cc; else CREG.x = cc;                                 \
        float h = sigm(gO) * tanhf(cc);                                       \
        if (e) hp.y = h; else hp.x = h;                                       \
      }                                                                       \
      h2 hh = { (_Float16)hp.x, (_Float16)hp.y };                             \
      int idx = band * 50 + 2 * pr;                                           \
      unsigned long long tw = ((unsigned long long)(GEN) << 32)               \
                            | (unsigned long long)__builtin_bit_cast(unsigned int, hh); \
      __hip_atomic_store(&xg[(((PH) * 8 + band) * 2 + il) * 25 + pr], tw,     \
                         __ATOMIC_RELAXED, __HIP_MEMORY_SCOPE_AGENT);         \
      STORES                                                                  \
    }

// poll 7 peer bands' tagged words: lid<350 -> (peer 7, il 2, pr 25)
#define POLL(PH, GEN, DESTS)                                                  \
    if (lid < 350) {                                                          \
      int p = lid / 50, w = lid % 50, il = w / 25, pr = w % 25;               \
      int pb = p + (p >= band);                                               \
      const unsigned int gexp = (GEN);                                        \
      unsigned long long v64;                                                 \
      while ((unsigned int)((v64 = __hip_atomic_load(                         \
                 &xg[(((PH) * 8 + pb) * 2 + il) * 25 + pr],                   \
                 __ATOMIC_RELAXED, __HIP_MEMORY_SCOPE_AGENT)) >> 32) != gexp) \
        __builtin_amdgcn_s_sleep(1);                                          \
      h2 hv = toh2((unsigned int)v64);                                        \
      int idx = pb * 50 + 2 * pr;                                             \
      DESTS                                                                   \
    }

  for (int t = 0; t < TT; ++t) {
    // -- phase 1: out-write(t-1) + L1 gates --
    if (t > 0 && lid < 32) {
      int oi = lid & 15, il = lid >> 4;
      int o = 8 * oi + band;
      if (o < NO) {
        float r = A.bout[o];
        #pragma unroll
        for (int s = 0; s < KS; ++s) r += pO[(s * 2 + il) * 16 + oi];
        A.out[((size_t)(2 * grp + il) * TT + (t - 1)) * NO + o] = r;
      }
    }
    GATES(W1b, J1, svh1[0], svh1[1])
    __syncthreads();
    // -- phase 2: L1 cell + x(t) staging + poll h1 --
    CELL(A.b1, c1, 0, 3u * t + 1u,
      soh[il][idx] = hh.x;      soh[il][idx + 1] = hh.y;
      svh1[il][80 + idx] = hh.x; svh1[il][81 + idx] = hh.y;
      svh2[il][3 + idx]  = hh.x; svh2[il][4 + idx]  = hh.y;
    )
    if (lid >= 512 && lid < 518) {
      int il = (lid - 512) / 3, cm = (lid - 512) % 3;
      _Float16 xv = (_Float16)A.x[((size_t)(2 * grp + il) * TT + t) * 3 + cm];
      svh2[il][cm] = xv; svh3[il][cm] = xv;
    }
    POLL(0, 3u * t + 1u,
      soh[il][idx] = hv.x;      soh[il][idx + 1] = hv.y;
      svh1[il][80 + idx] = hv.x; svh1[il][81 + idx] = hv.y;
      svh2[il][3 + idx]  = hv.x; svh2[il][4 + idx]  = hv.y;
    )
    __syncthreads();
    // -- phase 3: attention (waves 0,1 = items 0,1; replicated per band) --
    if (wv < 2) {
      const int il = wv;
      const h2* hO = (const h2*)soh[il];
      float m = 0.f;
      if (lane < 60) {
        const uint4* ww = (const uint4*)WWIN + lane * 25;
        const h2* hp = hO + (lane & 1) * 100;
        float acc = 0.f;
        #pragma unroll 5
        for (int p = 0; p < 25; ++p) {
          uint4 wq = ww[p];
          acc = FDOT2(toh2(wq.x), hp[4 * p + 0], acc);
          acc = FDOT2(toh2(wq.y), hp[4 * p + 1], acc);
          acc = FDOT2(toh2(wq.z), hp[4 * p + 2], acc);
          acc = FDOT2(toh2(wq.w), hp[4 * p + 3], acc);
        }
        m = acc;
      }
      m += __shfl_xor(m, 1);
      float mix = 0.f;
      if (lane < 60 && !(lane & 1)) mix = __expf(m + bwinr);
      float alpha[NK], beta[NK];
      #pragma unroll
      for (int k = 0; k < NK; ++k) {
        alpha[k] = __shfl(mix, 2 * k);
        beta[k]  = __shfl(mix, 20 + 2 * k);
        kapr[k] += __shfl(mix, 40 + 2 * k);
      }
      float u = (float)lane, phi = 0.f;
      #pragma unroll
      for (int k = 0; k < NK; ++k) {
        float d = kapr[k] - u;
        phi += alpha[k] * __expf(-beta[k] * d * d);
      }
      phi *= maskr;
      float w0a = 0.f, w1a = 0.f;
      #pragma unroll 8
      for (int uu2 = 0; uu2 < UU; ++uu2) {
        int   tu = __shfl(textr, uu2);
        float pu = __shfl(phi, uu2);
        w0a += (tu == lane)      ? pu : 0.f;
        w1a += (tu == lane + 64) ? pu : 0.f;
      }
      if (lane < VV) {
        _Float16 wh = (_Float16)w0a;
        svh1[il][3 + lane] = wh; svh2[il][403 + lane] = wh; svh3[il][403 + lane] = wh;
      }
      if (lane + 64 < VV) {
        _Float16 wh = (_Float16)w1a;
        svh1[il][67 + lane] = wh; svh2[il][467 + lane] = wh; svh3[il][467 + lane] = wh;
      }
    }
    __syncthreads();
    // -- phase 4: L2 gates --
    GATES(W2b, J23, svh2[0], svh2[1])
    __syncthreads();
    // -- phase 5: L2 cell + poll h2 --
    CELL(A.b2, c2r, 1, 3u * t + 2u,
      soh[il][400 + idx] = hh.x;  soh[il][401 + idx] = hh.y;
      svh2[il][480 + idx] = hh.x; svh2[il][481 + idx] = hh.y;
      svh3[il][3 + idx]   = hh.x; svh3[il][4 + idx]   = hh.y;
    )
    POLL(1, 3u * t + 2u,
      soh[il][400 + idx] = hv.x;  soh[il][401 + idx] = hv.y;
      svh2[il][480 + idx] = hv.x; svh2[il][481 + idx] = hv.y;
      svh3[il][3 + idx]   = hv.x; svh3[il][4 + idx]   = hv.y;
    )
    __syncthreads();
    // -- phase 6: L3 gates --
    GATES(W3b, J23, svh3[0], svh3[1])
    __syncthreads();
    // -- phase 7: L3 cell + out slices s<3 (h1|h2 only) + x(t+1) + poll h3 --
    CELL(A.b3, c3r, 2, 3u * t + 3u,
      soh[il][800 + idx] = hh.x;  soh[il][801 + idx] = hh.y;
      svh3[il][480 + idx] = hh.x; svh3[il][481 + idx] = hh.y;
    )
    if (lid >= 512 && lid < 518 && t + 1 < TT) {
      int il = (lid - 512) / 3, cm = (lid - 512) % 3;
      svh1[il][cm] = (_Float16)A.x[((size_t)(2 * grp + il) * TT + (t + 1)) * 3 + cm];
    }
    if (lid >= 64 && lid < 112) {            // threads 64..111: oi 16 x s 3
      int oi = (lid - 64) & 15, s = (lid - 64) >> 4;   // s in 0..2 (k<720<800)
      const uint4* Wp = WOb + (size_t)(s * JO) * 16 + oi;
      const uint4* p0 = (const uint4*)(&soh[0][s * 240]);
      const uint4* p1 = (const uint4*)(&soh[1][s * 240]);
      float a0 = 0.f, a1 = 0.f;
      #pragma unroll 3
      for (int j = 0; j < JO; ++j) {
        uint4 w = Wp[(size_t)j * 16];
        a0 = dot4(w, p0[j], a0); a1 = dot4(w, p1[j], a1);
      }
      pO[(s * 2 + 0) * 16 + oi] = a0;
      pO[(s * 2 + 1) * 16 + oi] = a1;
    }
    POLL(2, 3u * t + 3u,
      soh[il][800 + idx] = hv.x;  soh[il][801 + idx] = hv.y;
      svh3[il][480 + idx] = hv.x; svh3[il][481 + idx] = hv.y;
    )
    __syncthreads();
    // -- phase 8: out slices s=3,4 (need h3) --
    if (lid < 32) {
      int oi = lid & 15, s = 3 + (lid >> 4);
      const uint4* Wp = WOb + (size_t)(s * JO) * 16 + oi;
      const uint4* p0 = (const uint4*)(&soh[0][s * 240]);
      const uint4* p1 = (const uint4*)(&soh[1][s * 240]);
      float a0 = 0.f, a1 = 0.f;
      #pragma unroll 3
      for (int j = 0; j < JO; ++j) {
        uint4 w = Wp[(size_t)j * 16];
        a0 = dot4(w, p0[j], a0); a1 = dot4(w, p1[j], a1);
      }
      pO[(s * 2 + 0) * 16 + oi] = a0;
      pO[(s * 2 + 1) * 16 + oi] = a1;
    }
    __syncthreads();
  }
  // epilogue: out-write for t=599
  if (lid < 32) {
    int oi = lid & 15, il = lid >> 4;
    int o = 8 * oi + band;
    if (o < NO) {
      float r = A.bout[o];
      #pragma unroll
      for (int s = 0; s < KS; ++s) r += pO[(s * 2 + il) * 16 + oi];
      A.out[((size_t)(2 * grp + il) * TT + (TT - 1)) * NO + o] = r;
    }
  }
#undef GATES
#undef CELL
#undef POLL
}

extern "C" void kernel_launch(void* const* d_in, const int* in_sizes, int n_in,
                              void* d_out, int out_size, void* d_ws, size_t ws_size,
                              hipStream_t stream) {
  Args a;
  a.x    = (const float*)d_in[0];
  a.text = (const int*)  d_in[1];
  a.mask = (const float*)d_in[2];
  a.Wih1 = (const float*)d_in[3];  a.Whh1 = (const float*)d_in[4];  a.b1 = (const float*)d_in[5];
  a.Wih2 = (const float*)d_in[6];  a.Whh2 = (const float*)d_in[7];  a.b2 = (const float*)d_in[8];
  a.Wih3 = (const float*)d_in[9];  a.Whh3 = (const float*)d_in[10]; a.b3 = (const float*)d_in[11];
  a.Wwin = (const float*)d_in[12]; a.bwin = (const float*)d_in[13];
  a.Wout = (const float*)d_in[14]; a.bout = (const float*)d_in[15];
  a.out  = (float*)d_out;
  a.ws   = (float*)d_ws;
  void* kargs[] = { &a };
  hipLaunchCooperativeKernel((const void*)hsnet_kernel, dim3(NWG), dim3(NTH),
                             kargs, 0, stream);
}